// Round 1
// baseline (1366.173 us; speedup 1.0000x reference)
//
#include <hip/hip_runtime.h>

#define T_LEN 2048
#define DH 256

typedef short short8 __attribute__((ext_vector_type(8)));
typedef float f32x4 __attribute__((ext_vector_type(4)));

__device__ __forceinline__ unsigned short f2bf(float f) {
  unsigned u = __builtin_bit_cast(unsigned, f);
  u += 0x7fffu + ((u >> 16) & 1u);   // round-to-nearest-even
  return (unsigned short)(u >> 16);
}

// Raw WG barrier: flush this wave's LDS ops, barrier, and fence the scheduler.
// Deliberately does NOT drain vmcnt — global prefetch loads / output stores
// stay in flight across steps (no cross-wave hazard goes through global mem).
#define WG_BARRIER() do {                                   \
  __builtin_amdgcn_sched_barrier(0);                        \
  asm volatile("s_waitcnt lgkmcnt(0)" ::: "memory");        \
  __builtin_amdgcn_s_barrier();                             \
  __builtin_amdgcn_sched_barrier(0);                        \
} while (0)

// ---------------------------------------------------------------------------
// Phase 1: x_proj = x @ W_in + b_in, written into d_out (same [B*T, 256] shape).
// Grid 512 x 256 thr. Each WG: 128 rows. Wave w owns cols [64w, 64w+64).
// W_in fragments loaded once into VGPRs (bf16), A (x rows) loaded per 16-row slab.
// MFMA 16x16x32 layout: A[m][k]: m=lane&15, k=(lane>>4)*8+j ; B[k][c]: c=lane&15,
// same k; D: c=lane&15, m=(lane>>4)*4+r.  (fp32 accumulate)
// ---------------------------------------------------------------------------
__global__ __launch_bounds__(256, 1) void xproj_gemm(
    const float* __restrict__ x, const float* __restrict__ W_in,
    const float* __restrict__ b_in, float* __restrict__ out) {
  const int tid  = threadIdx.x;
  const int lane = tid & 63;
  const int w    = tid >> 6;
  const int l15  = lane & 15;
  const int lg   = lane >> 4;
  const int koff = lg * 8;
  const int m0   = blockIdx.x * 128;

  short8 Bf[4][8];
#pragma unroll
  for (int n = 0; n < 4; ++n) {
    const int c = 64 * w + 16 * n + l15;
#pragma unroll
    for (int kk = 0; kk < 8; ++kk) {
      short8 bf;
#pragma unroll
      for (int j = 0; j < 8; ++j)
        bf[j] = (short)f2bf(W_in[(32 * kk + koff + j) * DH + c]);
      Bf[n][kk] = bf;
    }
  }
  float bin[4];
#pragma unroll
  for (int n = 0; n < 4; ++n) bin[n] = b_in[64 * w + 16 * n + l15];

  for (int slab = 0; slab < 8; ++slab) {
    const float* xr = x + (size_t)(m0 + slab * 16 + l15) * DH;
    short8 A[8];
#pragma unroll
    for (int kk = 0; kk < 8; ++kk) {
      f32x4 v0 = *(const f32x4*)(xr + 32 * kk + koff);
      f32x4 v1 = *(const f32x4*)(xr + 32 * kk + koff + 4);
      short8 a;
      a[0] = f2bf(v0[0]); a[1] = f2bf(v0[1]); a[2] = f2bf(v0[2]); a[3] = f2bf(v0[3]);
      a[4] = f2bf(v1[0]); a[5] = f2bf(v1[1]); a[6] = f2bf(v1[2]); a[7] = f2bf(v1[3]);
      A[kk] = a;
    }
    f32x4 acc[4];
#pragma unroll
    for (int n = 0; n < 4; ++n) acc[n] = (f32x4){0.f, 0.f, 0.f, 0.f};
#pragma unroll
    for (int kk = 0; kk < 8; ++kk)
#pragma unroll
      for (int n = 0; n < 4; ++n)
        acc[n] = __builtin_amdgcn_mfma_f32_16x16x32_bf16(A[kk], Bf[n][kk], acc[n], 0, 0, 0);
#pragma unroll
    for (int n = 0; n < 4; ++n) {
      const int c = 64 * w + 16 * n + l15;
#pragma unroll
      for (int r = 0; r < 4; ++r)
        out[(size_t)(m0 + slab * 16 + lg * 4 + r) * DH + c] = acc[n][r] + bin[n];
    }
  }
}

// ---------------------------------------------------------------------------
// Phase 2: serial scan.  Grid 32 (one WG per batch) x 256 thr (4 waves).
// h kept as bf16 in a double-buffered 256-entry LDS row; W_h in VGPR fragments.
// x_proj consumed from d_out via 16-step LDS chunks with register prefetch
// (issue loads one chunk early, ds_write at the boundary => HBM latency hidden).
// Each step: A-frag ds_reads (4 lanes), 32 MFMA, 16-lane epilogue, 1 barrier.
// A-operand rows 1..15 are register zeros => only row 0 of D is meaningful.
// ---------------------------------------------------------------------------
__global__ __launch_bounds__(256, 1) void rnn_scan(
    const float* __restrict__ h0, const float* __restrict__ W_h,
    const float* __restrict__ b_h, float* __restrict__ out) {
  __shared__ __align__(16) unsigned short hbuf[2][256];
  __shared__ __align__(16) float xpb[2][16 * DH];

  const int tid  = threadIdx.x;
  const int lane = tid & 63;
  const int w    = tid >> 6;
  const int l15  = lane & 15;
  const int lg   = lane >> 4;
  const int koff = lg * 8;
  const int b    = blockIdx.x;
  float* outb = out + (size_t)b * T_LEN * DH;

  // Issue chunk-0 x_proj loads first so they fly under the W_h fragment load.
  f32x4 st[4];
#pragma unroll
  for (int i = 0; i < 4; ++i)
    st[i] = *(const f32x4*)(outb + i * 1024 + tid * 4);

  // W_h bf16 fragments: wave w owns cols [64w, 64w+64) as 4 16-col tiles.
  short8 Bf[4][8];
#pragma unroll
  for (int n = 0; n < 4; ++n) {
    const int c = 64 * w + 16 * n + l15;
#pragma unroll
    for (int kk = 0; kk < 8; ++kk) {
      short8 bf;
#pragma unroll
      for (int j = 0; j < 8; ++j)
        bf[j] = (short)f2bf(W_h[(32 * kk + koff + j) * DH + c]);
      Bf[n][kk] = bf;
    }
  }
  float bh[4];
#pragma unroll
  for (int n = 0; n < 4; ++n) bh[n] = b_h[64 * w + 16 * n + l15];

  // h init (bf16), chunk 0 into LDS, prefetch chunk 1 into regs.
  hbuf[0][tid] = f2bf(h0[b * DH + tid]);
#pragma unroll
  for (int i = 0; i < 4; ++i)
    *(f32x4*)(&xpb[0][i * 1024 + tid * 4]) = st[i];
#pragma unroll
  for (int i = 0; i < 4; ++i)
    st[i] = *(const f32x4*)(outb + 4096 + i * 1024 + tid * 4);
  __syncthreads();

  for (int t = 0; t < T_LEN; ++t) {
    // A fragments: row 0 = h (bf16), rows 1..15 = 0 (in registers).
    const unsigned short* hb = &hbuf[t & 1][0];
    short8 A[8];
#pragma unroll
    for (int kk = 0; kk < 8; ++kk) {
      short8 a = {0, 0, 0, 0, 0, 0, 0, 0};
      if (l15 == 0) a = *(const short8*)(hb + 32 * kk + koff);
      A[kk] = a;
    }

    f32x4 acc[4];
#pragma unroll
    for (int n = 0; n < 4; ++n) acc[n] = (f32x4){0.f, 0.f, 0.f, 0.f};
#pragma unroll
    for (int kk = 0; kk < 8; ++kk)
#pragma unroll
      for (int n = 0; n < 4; ++n)
        acc[n] = __builtin_amdgcn_mfma_f32_16x16x32_bf16(A[kk], Bf[n][kk], acc[n], 0, 0, 0);

    // Epilogue: valid output row is m=0 -> lanes 0..15, reg 0.
    if (lane < 16) {
      const float* xpt = &xpb[(t >> 4) & 1][(t & 15) * DH];
#pragma unroll
      for (int n = 0; n < 4; ++n) {
        const int c = 64 * w + 16 * n + lane;
        float v = acc[n][0] + xpt[c] + bh[n];
        v = fmaxf(v, 0.0f);
        outb[(size_t)t * DH + c] = v;                 // overwrite x_proj row with h_t
        hbuf[(t + 1) & 1][c] = f2bf(v);
      }
    }

    if ((t & 15) == 15) {
      WG_BARRIER();  // all reads of current xp chunk + h writes complete
      const int nc = (t >> 4) + 1;            // chunk to publish (regs -> LDS)
      if (nc < T_LEN / 16) {
#pragma unroll
        for (int i = 0; i < 4; ++i)
          *(f32x4*)(&xpb[nc & 1][i * 1024 + tid * 4]) = st[i];
        const int pc = nc + 1;                // prefetch following chunk
        if (pc < T_LEN / 16) {
#pragma unroll
          for (int i = 0; i < 4; ++i)
            st[i] = *(const f32x4*)(outb + (size_t)pc * 4096 + i * 1024 + tid * 4);
        }
      }
      WG_BARRIER();  // xp chunk visible before next step reads it
    } else {
      WG_BARRIER();  // h_{t+1} visible before next step's A-frag reads
    }
  }
}

extern "C" void kernel_launch(void* const* d_in, const int* in_sizes, int n_in,
                              void* d_out, int out_size, void* d_ws, size_t ws_size,
                              hipStream_t stream) {
  const float* x    = (const float*)d_in[0];
  const float* h0   = (const float*)d_in[1];
  const float* W_in = (const float*)d_in[2];
  const float* b_in = (const float*)d_in[3];
  const float* W_h  = (const float*)d_in[4];
  const float* b_h  = (const float*)d_in[5];
  float* out = (float*)d_out;

  hipLaunchKernelGGL(xproj_gemm, dim3(512), dim3(256), 0, stream, x, W_in, b_in, out);
  hipLaunchKernelGGL(rnn_scan, dim3(32), dim3(256), 0, stream, h0, W_h, b_h, out);
}

// Round 2
// 910.232 us; speedup vs baseline: 1.5009x; 1.5009x over previous
//
#include <hip/hip_runtime.h>

#define T_LEN 2048
#define DH 256
#define NCHUNK (T_LEN / 16)

typedef short short8 __attribute__((ext_vector_type(8)));
typedef float f32x4 __attribute__((ext_vector_type(4)));

__device__ __forceinline__ unsigned short f2bf(float f) {
  unsigned u = __builtin_bit_cast(unsigned, f);
  u += 0x7fffu + ((u >> 16) & 1u);   // round-to-nearest-even
  return (unsigned short)(u >> 16);
}

// Raw WG barrier: flush this wave's LDS ops, barrier, fence the scheduler.
// Deliberately does NOT drain vmcnt — prefetch loads / chunk stores stay in
// flight across steps (no cross-wave hazard goes through global memory).
#define WG_BARRIER() do {                                   \
  __builtin_amdgcn_sched_barrier(0);                        \
  asm volatile("s_waitcnt lgkmcnt(0)" ::: "memory");        \
  __builtin_amdgcn_s_barrier();                             \
  __builtin_amdgcn_sched_barrier(0);                        \
} while (0)

// ---------------------------------------------------------------------------
// Phase 1: out = x @ W_in + b_in + b_h   (b_h folded in so the scan epilogue
// is one add shorter). Grid 512 x 256 thr; wave w owns cols [64w, 64w+64).
// MFMA 16x16x32 bf16. A[m][k]: m=lane&15, k=(lane>>4)*8+j; B same k, c=lane&15;
// D: c=lane&15, m=(lane>>4)*4+r.
// ---------------------------------------------------------------------------
__global__ __launch_bounds__(256, 1) void xproj_gemm(
    const float* __restrict__ x, const float* __restrict__ W_in,
    const float* __restrict__ b_in, const float* __restrict__ b_h,
    float* __restrict__ out) {
  const int tid  = threadIdx.x;
  const int lane = tid & 63;
  const int w    = tid >> 6;
  const int l15  = lane & 15;
  const int lg   = lane >> 4;
  const int koff = lg * 8;
  const int m0   = blockIdx.x * 128;

  short8 Bf[4][8];
#pragma unroll
  for (int n = 0; n < 4; ++n) {
    const int c = 64 * w + 16 * n + l15;
#pragma unroll
    for (int kk = 0; kk < 8; ++kk) {
      short8 bf;
#pragma unroll
      for (int j = 0; j < 8; ++j)
        bf[j] = (short)f2bf(W_in[(32 * kk + koff + j) * DH + c]);
      Bf[n][kk] = bf;
    }
  }
  float bin[4];
#pragma unroll
  for (int n = 0; n < 4; ++n) {
    const int c = 64 * w + 16 * n + l15;
    bin[n] = b_in[c] + b_h[c];
  }

  for (int slab = 0; slab < 8; ++slab) {
    const float* xr = x + (size_t)(m0 + slab * 16 + l15) * DH;
    short8 A[8];
#pragma unroll
    for (int kk = 0; kk < 8; ++kk) {
      f32x4 v0 = *(const f32x4*)(xr + 32 * kk + koff);
      f32x4 v1 = *(const f32x4*)(xr + 32 * kk + koff + 4);
      short8 a;
      a[0] = f2bf(v0[0]); a[1] = f2bf(v0[1]); a[2] = f2bf(v0[2]); a[3] = f2bf(v0[3]);
      a[4] = f2bf(v1[0]); a[5] = f2bf(v1[1]); a[6] = f2bf(v1[2]); a[7] = f2bf(v1[3]);
      A[kk] = a;
    }
    f32x4 acc[4];
#pragma unroll
    for (int n = 0; n < 4; ++n) acc[n] = (f32x4){0.f, 0.f, 0.f, 0.f};
#pragma unroll
    for (int kk = 0; kk < 8; ++kk)
#pragma unroll
      for (int n = 0; n < 4; ++n)
        acc[n] = __builtin_amdgcn_mfma_f32_16x16x32_bf16(A[kk], Bf[n][kk], acc[n], 0, 0, 0);
#pragma unroll
    for (int n = 0; n < 4; ++n) {
      const int c = 64 * w + 16 * n + l15;
#pragma unroll
      for (int r = 0; r < 4; ++r)
        out[(size_t)(m0 + slab * 16 + lg * 4 + r) * DH + c] = acc[n][r] + bin[n];
    }
  }
}

// ---------------------------------------------------------------------------
// Phase 2: serial scan. Grid 32 (one WG per batch) x 512 thr (8 waves).
// Wave w owns cols [32w, 32w+32) -> Bf[2][8] = 64 VGPRs/lane (no spill).
// h: bf16 in double-buffered LDS row. Steady-state steps have ZERO vmem ops:
// x_proj consumed from LDS chunks (prefetched one chunk ahead into regs),
// h outputs staged in LDS xout and dumped with coalesced dwordx4 once per
// 16-step chunk, ordered after the prefetch loads (wait is vmcnt(2), never 0).
// A-operand rows 1..15 are register zeros set once before the loop.
// ---------------------------------------------------------------------------
__global__ __launch_bounds__(512, 2) void rnn_scan(
    const float* __restrict__ h0, const float* __restrict__ W_h,
    float* __restrict__ out) {
  __shared__ __align__(16) unsigned short hbuf[2][DH];
  __shared__ __align__(16) float xpb[2][16 * DH];
  __shared__ __align__(16) float xout[16 * DH];

  const int tid  = threadIdx.x;
  const int lane = tid & 63;
  const int w    = tid >> 6;         // 0..7
  const int l15  = lane & 15;
  const int lg   = lane >> 4;
  const int koff = lg * 8;
  const int b    = blockIdx.x;
  float* outb = out + (size_t)b * T_LEN * DH;

  // Issue chunk-0 x_proj loads first so they fly under the W_h fragment load.
  f32x4 st[2];
#pragma unroll
  for (int i = 0; i < 2; ++i)
    st[i] = *(const f32x4*)(outb + i * 2048 + tid * 4);

  // W_h bf16 fragments: wave w owns cols [32w, 32w+32) as 2 16-col tiles.
  short8 Bf[2][8];
#pragma unroll
  for (int n = 0; n < 2; ++n) {
    const int c = 32 * w + 16 * n + l15;
#pragma unroll
    for (int kk = 0; kk < 8; ++kk) {
      short8 bf;
#pragma unroll
      for (int j = 0; j < 8; ++j)
        bf[j] = (short)f2bf(W_h[(32 * kk + koff + j) * DH + c]);
      Bf[n][kk] = bf;
    }
  }

  if (tid < DH) hbuf[0][tid] = f2bf(h0[b * DH + tid]);
#pragma unroll
  for (int i = 0; i < 2; ++i)
    *(f32x4*)(&xpb[0][i * 2048 + tid * 4]) = st[i];
#pragma unroll
  for (int i = 0; i < 2; ++i)
    st[i] = *(const f32x4*)(outb + 4096 + i * 2048 + tid * 4);
  __syncthreads();

  // A fragments: rows 1..15 are zeros, set ONCE; only l15==0 lanes overwrite.
  short8 A[8];
#pragma unroll
  for (int kk = 0; kk < 8; ++kk) A[kk] = (short8){0, 0, 0, 0, 0, 0, 0, 0};

  for (int t = 0; t < T_LEN; ++t) {
    const unsigned short* hb = &hbuf[t & 1][0];
    if (l15 == 0) {
#pragma unroll
      for (int kk = 0; kk < 8; ++kk)
        A[kk] = *(const short8*)(hb + 32 * kk + koff);
    }
    // x_proj(+biases) for this step, read early (off the MFMA wait path).
    float xb[2];
    if (lane < 16) {
#pragma unroll
      for (int n = 0; n < 2; ++n)
        xb[n] = xpb[(t >> 4) & 1][(t & 15) * DH + 32 * w + 16 * n + lane];
    }

    // 16 MFMAs: 2 col-tiles x (2 sub-accumulators of depth 4).
    f32x4 ac[2][2];
#pragma unroll
    for (int n = 0; n < 2; ++n) {
      ac[n][0] = (f32x4){0.f, 0.f, 0.f, 0.f};
      ac[n][1] = (f32x4){0.f, 0.f, 0.f, 0.f};
    }
#pragma unroll
    for (int kk = 0; kk < 4; ++kk)
#pragma unroll
      for (int n = 0; n < 2; ++n)
        ac[n][0] = __builtin_amdgcn_mfma_f32_16x16x32_bf16(A[kk], Bf[n][kk], ac[n][0], 0, 0, 0);
#pragma unroll
    for (int kk = 4; kk < 8; ++kk)
#pragma unroll
      for (int n = 0; n < 2; ++n)
        ac[n][1] = __builtin_amdgcn_mfma_f32_16x16x32_bf16(A[kk], Bf[n][kk], ac[n][1], 0, 0, 0);

    // Valid output row is m=0 -> lanes 0..15, reg 0.
    if (lane < 16) {
#pragma unroll
      for (int n = 0; n < 2; ++n) {
        const int c = 32 * w + 16 * n + lane;
        float v = ac[n][0][0] + ac[n][1][0] + xb[n];
        v = fmaxf(v, 0.0f);
        xout[(t & 15) * DH + c] = v;           // staged for the chunk dump
        hbuf[(t + 1) & 1][c] = f2bf(v);
      }
    }

    if ((t & 15) == 15) {
      WG_BARRIER();  // all reads of xp chunk + h/xout writes complete
      const int cc = t >> 4;      // finished chunk
      const int nc = cc + 1;
      if (nc < NCHUNK) {
        // publish prefetched chunk (waits vmcnt(2): 2 stores newer than loads)
#pragma unroll
        for (int i = 0; i < 2; ++i)
          *(f32x4*)(&xpb[nc & 1][i * 2048 + tid * 4]) = st[i];
        const int pc = nc + 1;
        if (pc < NCHUNK) {
#pragma unroll
          for (int i = 0; i < 2; ++i)
            st[i] = *(const f32x4*)(outb + (size_t)pc * 4096 + i * 2048 + tid * 4);
        }
      }
      // dump finished h chunk: LDS -> regs -> coalesced global stores
      f32x4 o[2];
#pragma unroll
      for (int i = 0; i < 2; ++i)
        o[i] = *(const f32x4*)(&xout[i * 2048 + tid * 4]);
#pragma unroll
      for (int i = 0; i < 2; ++i)
        *(f32x4*)(outb + (size_t)cc * 4096 + i * 2048 + tid * 4) = o[i];
      WG_BARRIER();  // xpb chunk + xout reuse visible before next step
    } else {
      WG_BARRIER();  // h_{t+1} visible before next step's A-frag reads
    }
  }
}

extern "C" void kernel_launch(void* const* d_in, const int* in_sizes, int n_in,
                              void* d_out, int out_size, void* d_ws, size_t ws_size,
                              hipStream_t stream) {
  const float* x    = (const float*)d_in[0];
  const float* h0   = (const float*)d_in[1];
  const float* W_in = (const float*)d_in[2];
  const float* b_in = (const float*)d_in[3];
  const float* W_h  = (const float*)d_in[4];
  const float* b_h  = (const float*)d_in[5];
  float* out = (float*)d_out;

  hipLaunchKernelGGL(xproj_gemm, dim3(512), dim3(256), 0, stream, x, W_in, b_in, b_h, out);
  hipLaunchKernelGGL(rnn_scan, dim3(32), dim3(512), 0, stream, h0, W_h, out);
}